// Round 3
// baseline (64.936 us; speedup 1.0000x reference)
//
#include <hip/hip_runtime.h>
#include <math.h>

#define NMAT (192*192*192)   // 7,077,888 matrices
#define MPB  1024            // matrices per block (4 per thread, 256 threads)

__global__ __launch_bounds__(256, 4) void eig3_kernel(const float4* __restrict__ H4,
                                                      float4* __restrict__ out4) {
    __shared__ float lds[MPB * 9];          // 36 KB
    float4* lds4 = (float4*)lds;
    const int t = threadIdx.x;
    const long long blk = blockIdx.x;

    // Stage 1024 matrices = 2304 float4, perfectly coalesced.
    const long long ibase = blk * 2304LL;
#pragma unroll
    for (int k = 0; k < 9; ++k)
        lds4[t + 256 * k] = H4[ibase + t + 256 * k];
    __syncthreads();

    float res[4][3];
#pragma unroll
    for (int s = 0; s < 4; ++s) {
        const int m = t + 256 * s;          // strided ownership -> conflict-free LDS reads
        float h[9];
#pragma unroll
        for (int j = 0; j < 9; ++j)
            h[j] = lds[m * 9 + j];

        const float q = (h[0] + h[4] + h[8]) * (1.0f / 3.0f);
        const float c00 = h[0] - q, c01 = h[1],     c02 = h[2];
        const float c10 = h[3],     c11 = h[4] - q, c12 = h[5];
        const float c20 = h[6],     c21 = h[7],     c22 = h[8] - q;
        const float ss = c00*c00 + c01*c01 + c02*c02
                       + c10*c10 + c11*c11 + c12*c12
                       + c20*c20 + c21*c21 + c22*c22;
        const float p = sqrtf(ss * (1.0f / 6.0f));
        const float inv = __builtin_amdgcn_rcpf(p + 1e-10f);   // v_rcp_f32, ~1 ulp

        // det(C) directly; det(B) = det(C) * inv^3
        const float detC = c00*(c11*c22 - c12*c21)
                         - c01*(c10*c22 - c12*c20)
                         + c02*(c10*c21 - c11*c20);
        const float inv3 = inv * inv * inv;
        const float x = fminf(fmaxf(0.5f * detC * inv3, -1.0f), 1.0f);

        // fast acos (Abramowitz-Stegun 4.4.45, |err| <= 6.7e-5 rad)
        const float u = fabsf(x);
        const float sq = sqrtf(1.0f - u);
        const float poly = 1.5707288f + u*(-0.2121144f + u*(0.0742610f + u*(-0.0187293f)));
        const float ac = sq * poly;                         // acos(|x|)
        const float acx = (x >= 0.0f) ? ac : (3.14159265358979f - ac);
        const float theta = acx * (1.0f / 3.0f);

        float st, ct;
        __sincosf(theta, &st, &ct);
        const float r3 = 1.73205080756887729f;   // sqrt(3)
        const float e0 = 2.0f * p * ct + q;
        const float e1 = p * (-ct - r3 * st) + q;
        const float e2 = p * (-ct + r3 * st) + q;

        // 3-op sort: min3 / med3 / max3
        const float lo  = fminf(fminf(e0, e1), e2);
        const float hi  = fmaxf(fmaxf(e0, e1), e2);
        const float mid = __builtin_amdgcn_fmed3f(e0, e1, e2);
        res[s][0] = lo; res[s][1] = mid; res[s][2] = hi;
    }
    __syncthreads();   // lds reused for output staging

#pragma unroll
    for (int s = 0; s < 4; ++s) {
        const int m = t + 256 * s;
        lds[m * 3 + 0] = res[s][0];
        lds[m * 3 + 1] = res[s][1];
        lds[m * 3 + 2] = res[s][2];
    }
    __syncthreads();

    // 1024 matrices * 3 floats = 768 float4, coalesced.
    const long long obase = blk * 768LL;
#pragma unroll
    for (int k = 0; k < 3; ++k)
        out4[obase + t + 256 * k] = lds4[t + 256 * k];
}

extern "C" void kernel_launch(void* const* d_in, const int* in_sizes, int n_in,
                              void* d_out, int out_size, void* d_ws, size_t ws_size,
                              hipStream_t stream) {
    const float4* H4 = (const float4*)d_in[0];
    float4* out4 = (float4*)d_out;
    const int nblocks = NMAT / MPB;   // 6912, no tail
    eig3_kernel<<<nblocks, 256, 0, stream>>>(H4, out4);
}

// Round 4
// 54.229 us; speedup vs baseline: 1.1974x; 1.1974x over previous
//
#include <hip/hip_runtime.h>
#include <math.h>

#define NMAT (192*192*192)   // 7,077,888 matrices
#define MPB  1024            // matrices per block (4 per thread, 256 threads)

typedef float vfloat4 __attribute__((ext_vector_type(4)));

__global__ __launch_bounds__(256, 4) void eig3_kernel(const float4* __restrict__ H4,
                                                      float4* __restrict__ out4) {
    __shared__ float lds[MPB * 9];          // 36 KB
    float4* lds4 = (float4*)lds;
    const int t = threadIdx.x;
    const long long blk = blockIdx.x;
    const long long ibase = blk * 2304LL;

    // Async global->LDS staging: 9 x global_load_lds_dwordx4 per thread.
    // LDS dest = wave-uniform base + lane*16 (lds4[w*64 + 256k + lane]) -- legal layout.
#pragma unroll
    for (int k = 0; k < 9; ++k) {
        __builtin_amdgcn_global_load_lds(
            (const __attribute__((address_space(1))) void*)(H4 + ibase + t + 256 * k),
            (__attribute__((address_space(3))) void*)(lds4 + t + 256 * k),
            16, 0, 0);
    }
    __syncthreads();   // compiler emits vmcnt(0) before barrier -> staging complete

    float res[4][3];
#pragma unroll
    for (int s = 0; s < 4; ++s) {
        const int m = t + 256 * s;          // strided ownership -> conflict-free LDS reads
        float h[9];
#pragma unroll
        for (int j = 0; j < 9; ++j)
            h[j] = lds[m * 9 + j];

        const float q = (h[0] + h[4] + h[8]) * (1.0f / 3.0f);
        const float c00 = h[0] - q, c01 = h[1],     c02 = h[2];
        const float c10 = h[3],     c11 = h[4] - q, c12 = h[5];
        const float c20 = h[6],     c21 = h[7],     c22 = h[8] - q;
        const float ss = c00*c00 + c01*c01 + c02*c02
                       + c10*c10 + c11*c11 + c12*c12
                       + c20*c20 + c21*c21 + c22*c22;
        const float p = sqrtf(ss * (1.0f / 6.0f));
        const float inv = __builtin_amdgcn_rcpf(p + 1e-10f);

        const float detC = c00*(c11*c22 - c12*c21)
                         - c01*(c10*c22 - c12*c20)
                         + c02*(c10*c21 - c11*c20);
        const float inv3 = inv * inv * inv;
        const float x = fminf(fmaxf(0.5f * detC * inv3, -1.0f), 1.0f);

        // fast acos (Abramowitz-Stegun 4.4.45, |err| <= 6.7e-5 rad)
        const float u = fabsf(x);
        const float sq = sqrtf(1.0f - u);
        const float poly = 1.5707288f + u*(-0.2121144f + u*(0.0742610f + u*(-0.0187293f)));
        const float ac = sq * poly;
        const float acx = (x >= 0.0f) ? ac : (3.14159265358979f - ac);
        const float theta = acx * (1.0f / 3.0f);

        float st, ct;
        __sincosf(theta, &st, &ct);
        const float r3 = 1.73205080756887729f;   // sqrt(3)
        const float e0 = 2.0f * p * ct + q;
        const float e1 = p * (-ct - r3 * st) + q;
        const float e2 = p * (-ct + r3 * st) + q;

        const float lo  = fminf(fminf(e0, e1), e2);
        const float hi  = fmaxf(fmaxf(e0, e1), e2);
        const float mid = __builtin_amdgcn_fmed3f(e0, e1, e2);
        res[s][0] = lo; res[s][1] = mid; res[s][2] = hi;
    }
    __syncthreads();   // lds reused for output staging

#pragma unroll
    for (int s = 0; s < 4; ++s) {
        const int m = t + 256 * s;
        lds[m * 3 + 0] = res[s][0];
        lds[m * 3 + 1] = res[s][1];
        lds[m * 3 + 2] = res[s][2];
    }
    __syncthreads();

    // Coalesced non-temporal output: 768 float4 per block, zero reuse -> bypass caches.
    const long long obase = blk * 768LL;
#pragma unroll
    for (int k = 0; k < 3; ++k) {
        vfloat4 v = *(vfloat4*)&lds4[t + 256 * k];
        __builtin_nontemporal_store(v, (vfloat4*)(out4 + obase + t + 256 * k));
    }
}

extern "C" void kernel_launch(void* const* d_in, const int* in_sizes, int n_in,
                              void* d_out, int out_size, void* d_ws, size_t ws_size,
                              hipStream_t stream) {
    const float4* H4 = (const float4*)d_in[0];
    float4* out4 = (float4*)d_out;
    const int nblocks = NMAT / MPB;   // 6912, no tail
    eig3_kernel<<<nblocks, 256, 0, stream>>>(H4, out4);
}